// Round 3
// baseline (667.115 us; speedup 1.0000x reference)
//
#include <hip/hip_runtime.h>
#include <hip/hip_bf16.h>
#include <stdint.h>

// ---------------------------------------------------------------------------
// TernaryLinear: out[b,s,o] = t * sum_i x[b,s,i] * q[o,i]
//   q = ternary(weight) in {-1,0,+1}; t = clip(round(1/(mean|W|+eps)),-1,1)
// R2: 32x32x16 MFMA (2382 vs 2075 TF ceiling, half the MFMA issue slots),
//     fused single prep dispatch, XCD-aware block remap (4 B-panels/XCD L2).
//     KEEP: XOR-swizzled LDS layout (R1 win: conflicts 1e8 -> 0).
// ---------------------------------------------------------------------------

typedef __bf16 bf16x8  __attribute__((ext_vector_type(8)));
typedef float  f32x16  __attribute__((ext_vector_type(16)));

#define EPS 1e-7f
#define NPART 4096   // partial-sum slots (prep kernel grid size)

__device__ __forceinline__ void async_load16(const void* g, void* l) {
    __builtin_amdgcn_global_load_lds(
        (__attribute__((address_space(1))) void*)(const_cast<void*>(g)),
        (__attribute__((address_space(3))) void*)l,
        16, 0, 0);
}

__device__ __forceinline__ unsigned short f2bf_rne(float f) {
    unsigned u = __float_as_uint(f);
    unsigned r = (u + 0x7fffu + ((u >> 16) & 1u)) >> 16;
    return (unsigned short)r;
}

// Reduce NPART partials -> scalar scale t. Redundant per-wave (L2-hot 16KB).
__device__ __forceinline__ float scale_from_partials(const float* __restrict__ partials,
                                                     float invCount) {
    const int lane = threadIdx.x & 63;
    const float4* p4 = (const float4*)partials;   // NPART/4 = 1024 entries
    float s = 0.0f;
    #pragma unroll
    for (int j = 0; j < NPART / 4 / 64; ++j) {
        float4 v = p4[lane + 64 * j];
        s += v.x + v.y + v.z + v.w;
    }
    #pragma unroll
    for (int off = 32; off > 0; off >>= 1) s += __shfl_down(s, off, 64);
    s = __shfl(s, 0, 64);
    float mean = s * invCount;
    float gp = 1.0f / (mean + EPS);
    return fminf(fmaxf(rintf(gp), -1.0f), 1.0f);  // rintf = RNE = half-to-even
}

__device__ __forceinline__ unsigned short tern_bf16(float w) {
    // +1 -> 0x3F80, -1 -> 0xBF80, 0 -> 0x0000 (exact bf16 bit patterns)
    return (w > 0.5f) ? (unsigned short)0x3F80u
         : ((w < -0.5f) ? (unsigned short)0xBF80u : (unsigned short)0u);
}

// ---- fused prep: quantize W -> bf16 ternary (+abs partials), x -> bf16 -----

__global__ __launch_bounds__(256) void prep(
    const float* __restrict__ x, const float* __restrict__ w,
    ushort4* __restrict__ xb, ushort4* __restrict__ qb,
    float* __restrict__ partials, int xn4, int wn4)
{
    int tid = blockIdx.x * blockDim.x + threadIdx.x;
    int stride = gridDim.x * blockDim.x;
    float s = 0.0f;
    for (int i = tid; i < wn4; i += stride) {
        float4 v = ((const float4*)w)[i];
        s += fabsf(v.x) + fabsf(v.y) + fabsf(v.z) + fabsf(v.w);
        ushort4 r;
        r.x = tern_bf16(v.x); r.y = tern_bf16(v.y);
        r.z = tern_bf16(v.z); r.w = tern_bf16(v.w);
        qb[i] = r;
    }
    for (int i = tid; i < xn4; i += stride) {
        float4 v = ((const float4*)x)[i];
        ushort4 r;
        r.x = f2bf_rne(v.x); r.y = f2bf_rne(v.y);
        r.z = f2bf_rne(v.z); r.w = f2bf_rne(v.w);
        xb[i] = r;
    }
    #pragma unroll
    for (int off = 32; off > 0; off >>= 1) s += __shfl_down(s, off, 64);
    __shared__ float psum[4];
    int lane = threadIdx.x & 63, wid = threadIdx.x >> 6;
    if (lane == 0) psum[wid] = s;
    __syncthreads();
    if (threadIdx.x == 0)
        partials[blockIdx.x] = psum[0] + psum[1] + psum[2] + psum[3];
}

// ---- bf16 MFMA GEMM (B^T layout: out[m,n] = t * sum_k A[m,k]*B[n,k]) -------
// 32x32x16 MFMA. LDS: tile 128 rows x 8 chunks of 16B; chunk (row,cc) at slot
// row*8 + (cc ^ (row&7)) — keeps global_load_lds's uniform-base+lane*16 rule
// AND conflict-free fragment ds_read_b128 (R1-verified: SQ_LDS_BANK_CONFLICT=0).

#define BM 128
#define BN 128
#define BK 64

__global__ __launch_bounds__(256) void gemm_bt(
    const __bf16* __restrict__ A,   // [M,K] row-major bf16
    const __bf16* __restrict__ B,   // [N,K] row-major bf16 (ternary)
    float* __restrict__ C,          // [M,N] row-major fp32
    const float* __restrict__ partials,
    int N, int K, float invCount, int mPan, int nPan)
{
    __shared__ __bf16 As[BM * BK];
    __shared__ __bf16 Bs[BN * BK];

    const int t    = threadIdx.x;
    const int lane = t & 63;
    const int wid  = t >> 6;

    // XCD-aware remap: each XCD owns nPan/8 consecutive B-panels (4MB = 1 L2),
    // sweeping all M for each. Consecutive gids round-robin XCDs (heuristic;
    // correctness never depends on it).
    int gid = blockIdx.y * gridDim.x + blockIdx.x;
    int mIdx, nIdx;
    if ((nPan & 7) == 0 && ((mPan * nPan) & 7) == 0) {
        int xcd = gid & 7;
        int local = gid >> 3;                  // per-XCD sequence
        mIdx = local % mPan;
        nIdx = xcd * (nPan >> 3) + (local / mPan);
    } else {
        nIdx = gid % nPan;
        mIdx = gid / nPan;
    }

    const int mBase = mIdx * BM;
    const int nBase = nIdx * BN;
    const int wm = (wid >> 1) * 64;   // wave row offset in tile
    const int wn = (wid & 1) * 64;    // wave col offset in tile
    const int l31   = lane & 31;
    const int khalf = lane >> 5;      // which 8-wide k group

    f32x16 acc[2][2] = {};

    const __bf16* gA = A + (size_t)mBase * K;
    const __bf16* gB = B + (size_t)nBase * K;

    for (int k0 = 0; k0 < K; k0 += BK) {
        #pragma unroll
        for (int i = 0; i < 4; ++i) {
            int ch = i * 256 + t;
            int row = ch >> 3, sc = ch & 7;
            int cc = sc ^ (row & 7);                 // source chunk for this slot
            async_load16(gA + (size_t)row * K + k0 + cc * 8, &As[ch * 8]);
        }
        #pragma unroll
        for (int i = 0; i < 4; ++i) {
            int ch = i * 256 + t;
            int row = ch >> 3, sc = ch & 7;
            int cc = sc ^ (row & 7);
            async_load16(gB + (size_t)row * K + k0 + cc * 8, &Bs[ch * 8]);
        }
        __syncthreads();   // drains vmcnt (LDS writes) + barrier

        #pragma unroll
        for (int ks = 0; ks < BK; ks += 16) {
            const int cc = (ks >> 3) + khalf;        // logical 16B chunk 0..7
            bf16x8 af[2], bfr[2];
            #pragma unroll
            for (int mt = 0; mt < 2; ++mt) {
                int row = wm + mt * 32 + l31;
                af[mt] = *(const bf16x8*)&As[(row * 8 + (cc ^ (row & 7))) * 8];
            }
            #pragma unroll
            for (int nt = 0; nt < 2; ++nt) {
                int row = wn + nt * 32 + l31;
                bfr[nt] = *(const bf16x8*)&Bs[(row * 8 + (cc ^ (row & 7))) * 8];
            }
            #pragma unroll
            for (int mt = 0; mt < 2; ++mt)
                #pragma unroll
                for (int nt = 0; nt < 2; ++nt)
                    acc[mt][nt] = __builtin_amdgcn_mfma_f32_32x32x16_bf16(
                        af[mt], bfr[nt], acc[mt][nt], 0, 0, 0);
        }
        __syncthreads();   // all reads done before next stage overwrites LDS
    }

    const float tscale = scale_from_partials(partials, invCount);

    // 32x32 C/D layout (m74/m101): col = lane&31, row = (r&3) + 8*(r>>2) + 4*khalf
    #pragma unroll
    for (int mt = 0; mt < 2; ++mt) {
        #pragma unroll
        for (int nt = 0; nt < 2; ++nt) {
            #pragma unroll
            for (int r = 0; r < 16; ++r) {
                int row = mBase + wm + mt * 32 + (r & 3) + 8 * (r >> 2) + 4 * khalf;
                int col = nBase + wn + nt * 32 + l31;
                C[(size_t)row * N + col] = tscale * acc[mt][nt][r];
            }
        }
    }
}

// ---- fallback (ws too small): fp32 tiled GEMM with on-the-fly quantize ----

__global__ void gemm_fallback(const float* __restrict__ x, const float* __restrict__ w,
                              float* __restrict__ out, const float* __restrict__ partials,
                              int N, int K, float invCount)
{
    __shared__ float xs[16][17];
    __shared__ float qs[16][17];
    int tx = threadIdx.x & 15;
    int ty = threadIdx.x >> 4;
    int row = blockIdx.y * 16 + ty;
    int col = blockIdx.x * 16 + tx;
    float acc = 0.0f;
    for (int k0 = 0; k0 < K; k0 += 16) {
        xs[ty][tx] = x[(size_t)row * K + k0 + tx];
        float wv = w[(size_t)(blockIdx.x * 16 + ty) * K + k0 + tx];
        qs[ty][tx] = (wv > 0.5f) ? 1.0f : ((wv < -0.5f) ? -1.0f : 0.0f);
        __syncthreads();
        #pragma unroll
        for (int j = 0; j < 16; ++j) acc += xs[ty][j] * qs[tx][j];
        __syncthreads();
    }
    float tscale = scale_from_partials(partials, invCount);
    out[(size_t)row * N + col] = tscale * acc;
}

__global__ __launch_bounds__(256) void absmean_only(
    const float* __restrict__ w, float* __restrict__ partials, int n4)
{
    int tid = blockIdx.x * blockDim.x + threadIdx.x;
    int stride = gridDim.x * blockDim.x;
    float s = 0.0f;
    for (int i = tid; i < n4; i += stride) {
        float4 v = ((const float4*)w)[i];
        s += fabsf(v.x) + fabsf(v.y) + fabsf(v.z) + fabsf(v.w);
    }
    #pragma unroll
    for (int off = 32; off > 0; off >>= 1) s += __shfl_down(s, off, 64);
    __shared__ float psum[4];
    int lane = threadIdx.x & 63, wid = threadIdx.x >> 6;
    if (lane == 0) psum[wid] = s;
    __syncthreads();
    if (threadIdx.x == 0)
        partials[blockIdx.x] = psum[0] + psum[1] + psum[2] + psum[3];
}

// ---------------------------------------------------------------------------

extern "C" void kernel_launch(void* const* d_in, const int* in_sizes, int n_in,
                              void* d_out, int out_size, void* d_ws, size_t ws_size,
                              hipStream_t stream) {
    const float* x = (const float*)d_in[0];
    const float* w = (const float*)d_in[1];
    float* out = (float*)d_out;

    const int K = 4096;
    const int M = in_sizes[0] / K;       // 8192
    const int N = in_sizes[1] / K;       // 4096
    const float invCount = 1.0f / (float)(in_sizes[1]);

    float* partials = (float*)d_ws;                       // NPART floats = 16 KB
    const size_t base = NPART * sizeof(float);
    const size_t need = base + (size_t)M * K * 2 + (size_t)N * K * 2;

    if (ws_size >= need) {
        __bf16* xb = (__bf16*)((char*)d_ws + base);
        __bf16* qb = (__bf16*)((char*)d_ws + base + (size_t)M * K * 2);

        int xn4 = (M * K) / 4;
        int wn4 = (N * K) / 4;
        prep<<<NPART, 256, 0, stream>>>(x, w, (ushort4*)xb, (ushort4*)qb,
                                        partials, xn4, wn4);

        int mPan = M / BM, nPan = N / BN;
        dim3 grid(nPan, mPan);
        gemm_bt<<<grid, 256, 0, stream>>>(xb, qb, out, partials, N, K, invCount,
                                          mPan, nPan);
    } else {
        absmean_only<<<NPART, 256, 0, stream>>>(w, partials, in_sizes[1] / 4);
        dim3 grid(N / 16, M / 16);
        gemm_fallback<<<grid, 256, 0, stream>>>(x, w, out, partials, N, K, invCount);
    }
}